// Round 1
// baseline (3573.146 us; speedup 1.0000x reference)
//
#include <hip/hip_runtime.h>
#include <hip/hip_bf16.h>

#define N_ATOMS 25000
#define N_PAIRS 500000
#define N_PROP 16
#define C 64
#define DEPTH 4

__device__ __forceinline__ float tanh_fast(float x) {
    float xc = fminf(9.0f, fmaxf(-9.0f, x));
    float e = __expf(-2.0f * xc);
    return (1.0f - e) / (1.0f + e);
}

// ---------------- atom-level MLP: h = tanh(tanh(p@W1+b1)@W2+b2), plus acc init
template <int K, bool IS_D0>
__global__ __launch_bounds__(256)
void atom_mlp(const float* __restrict__ p_in,
              const float* __restrict__ W1, const float* __restrict__ b1,
              const float* __restrict__ W2, const float* __restrict__ b2,
              const float* __restrict__ res0_w,
              float* __restrict__ h_out, float* __restrict__ acc_out) {
    __shared__ float sP[4][64];
    __shared__ float sH[4][64];
    int tid = threadIdx.x;
    int al = tid >> 6, c = tid & 63;
    int a = blockIdx.x * 4 + al;
    if (c < K) sP[al][c] = p_in[a * K + c];
    __syncthreads();
    float s = b1[c];
#pragma unroll
    for (int k = 0; k < K; ++k) s += sP[al][k] * W1[k * 64 + c];
    float t1 = tanh_fast(s);
    // acc init: d0 -> p@res0_w ; else copy p
    float r;
    if (IS_D0) {
        r = 0.f;
#pragma unroll
        for (int k = 0; k < 16; ++k) r += sP[al][k] * res0_w[k * 64 + c];
    } else {
        r = sP[al][c];
    }
    acc_out[a * 64 + c] = r;
    sH[al][c] = t1;
    __syncthreads();
    float s2 = b2[c];
#pragma unroll
    for (int k = 0; k < 64; ++k) s2 += sH[al][k] * W2[k * 64 + c];
    h_out[a * 64 + c] = tanh_fast(s2);
}

// ---------------- output head: o = tanh(tanh(p@W1+b1)@W2+b2); out += o@wo
__global__ __launch_bounds__(256)
void out_kernel(const float* __restrict__ p,
                const float* __restrict__ W1, const float* __restrict__ b1,
                const float* __restrict__ W2, const float* __restrict__ b2,
                const float* __restrict__ wo,
                float* __restrict__ out, int store) {
    __shared__ float sP[4][64];
    __shared__ float sH[4][64];
    int tid = threadIdx.x;
    int al = tid >> 6, c = tid & 63;
    int a = blockIdx.x * 4 + al;
    sP[al][c] = p[a * 64 + c];
    __syncthreads();
    float s = b1[c];
#pragma unroll
    for (int k = 0; k < 64; ++k) s += sP[al][k] * W1[k * 64 + c];
    sH[al][c] = tanh_fast(s);
    __syncthreads();
    float s2 = b2[c];
#pragma unroll
    for (int k = 0; k < 64; ++k) s2 += sH[al][k] * W2[k * 64 + c];
    float v = tanh_fast(s2) * wo[c];
    // wave reduction over 64 lanes (one atom per wave)
#pragma unroll
    for (int off = 32; off > 0; off >>= 1) v += __shfl_down(v, off, 64);
    if (c == 0) {
        if (store) out[a] = v;
        else out[a] += v;
    }
}

// ---------------- fused pair pipeline
// gather pij -> G1(128->64) -> G2(64->256)+einsum(basis) -> ii1 -> ii2 -> atomic scatter
#define TILE 64
#define PITCH 68

__global__ __launch_bounds__(512)
void pair_kernel(const float* __restrict__ h,
                 const int* __restrict__ ind2,
                 const float* __restrict__ basis,
                 const float* __restrict__ piW1, const float* __restrict__ piB1,
                 const float* __restrict__ piW2, const float* __restrict__ piB2,
                 const float* __restrict__ iiW1, const float* __restrict__ iiW2,
                 float* __restrict__ accp) {
    __shared__ float sW1[128 * 64];       // 32 KB  pi_w1 [k][c]
    __shared__ float sWa[64 * 64];        // 16 KB  ii_w1
    __shared__ float sWb[64 * 64];        // 16 KB  ii_w2
    __shared__ float sB1[64];
    __shared__ float sB2[256];
    __shared__ float sA[128 * PITCH];     // 34.8 KB pij^T [k][m]
    __shared__ float sT0[64 * PITCH];     // 17.4 KB transpose ping
    __shared__ float sT1[64 * PITCH];     // 17.4 KB transpose pong
    __shared__ float sBas[64 * 4];
    __shared__ int sIdx[64];

    int tid = threadIdx.x;
    for (int i = tid; i < 128 * 64; i += 512) sW1[i] = piW1[i];
    for (int i = tid; i < 64 * 64; i += 512) { sWa[i] = iiW1[i]; sWb[i] = iiW2[i]; }
    if (tid < 64) sB1[tid] = piB1[tid];
    if (tid < 256) sB2[tid] = piB2[tid];
    __syncthreads();

    int mg = tid >> 5;        // 0..15
    int cg = tid & 31;        // 0..31
    int m0 = mg * 4;
    int c0 = cg * 2;

    const int nTiles = (N_PAIRS + TILE - 1) / TILE;
    for (int tile = blockIdx.x; tile < nTiles; tile += gridDim.x) {
        int base = tile * TILE;
        if (tid < 64) {
            int p = base + tid;
            sIdx[tid] = (p < N_PAIRS) ? ind2[2 * p] : 0;
        }
        if (tid < 256) {
            int m = tid >> 2, b = tid & 3;
            int p = base + m;
            sBas[tid] = (p < N_PAIRS) ? basis[4 * p + b] : 0.f;
        }
        // stage pij transposed: sA[k][m]
#pragma unroll
        for (int r = 0; r < 16; ++r) {
            int e = r * 512 + tid;
            int m = e >> 7, k = e & 127;
            int p = base + m;
            float v = 0.f;
            if (p < N_PAIRS) {
                int row = (k < 64) ? ind2[2 * p] : ind2[2 * p + 1];
                v = h[row * 64 + (k & 63)];
            }
            sA[k * PITCH + m] = v;
        }
        __syncthreads();

        // ---- G1: [64p x 128] @ [128 x 64] + b1, tanh
        float a1[4][2];
        {
            float acc[4][2];
#pragma unroll
            for (int mi = 0; mi < 4; ++mi) { acc[mi][0] = sB1[c0]; acc[mi][1] = sB1[c0 + 1]; }
#pragma unroll 4
            for (int k = 0; k < 128; ++k) {
                float4 av = *(const float4*)&sA[k * PITCH + m0];
                float2 wv = *(const float2*)&sW1[k * 64 + c0];
                acc[0][0] += av.x * wv.x; acc[0][1] += av.x * wv.y;
                acc[1][0] += av.y * wv.x; acc[1][1] += av.y * wv.y;
                acc[2][0] += av.z * wv.x; acc[2][1] += av.z * wv.y;
                acc[3][0] += av.w * wv.x; acc[3][1] += av.w * wv.y;
            }
#pragma unroll
            for (int mi = 0; mi < 4; ++mi)
#pragma unroll
                for (int j = 0; j < 2; ++j) a1[mi][j] = tanh_fast(acc[mi][j]);
        }
#pragma unroll
        for (int j = 0; j < 2; ++j) {
            float4 v = make_float4(a1[0][j], a1[1][j], a1[2][j], a1[3][j]);
            *(float4*)&sT0[(c0 + j) * PITCH + m0] = v;
        }
        __syncthreads();

        // ---- G2: [64p x 64] @ [64 x 256] + b2, tanh, einsum with basis -> inter[64p x 64]
        float inter[4][2] = {{0.f, 0.f}, {0.f, 0.f}, {0.f, 0.f}, {0.f, 0.f}};
        {
            float acc[4][8];
#pragma unroll
            for (int mi = 0; mi < 4; ++mi)
#pragma unroll
                for (int jj = 0; jj < 8; ++jj) acc[mi][jj] = sB2[8 * cg + jj];
#pragma unroll 2
            for (int k = 0; k < 64; ++k) {
                float4 av = *(const float4*)&sT0[k * PITCH + m0];
                float4 w0 = *(const float4*)&piW2[k * 256 + 8 * cg];
                float4 w1 = *(const float4*)&piW2[k * 256 + 8 * cg + 4];
                float wr[8] = {w0.x, w0.y, w0.z, w0.w, w1.x, w1.y, w1.z, w1.w};
                float ar[4] = {av.x, av.y, av.z, av.w};
#pragma unroll
                for (int mi = 0; mi < 4; ++mi)
#pragma unroll
                    for (int jj = 0; jj < 8; ++jj) acc[mi][jj] += ar[mi] * wr[jj];
            }
#pragma unroll
            for (int mi = 0; mi < 4; ++mi)
#pragma unroll
                for (int jj = 0; jj < 8; ++jj) {
                    float t = tanh_fast(acc[mi][jj]) * sBas[(m0 + mi) * 4 + (jj & 3)];
                    inter[mi][jj >> 2] += t;
                }
        }
#pragma unroll
        for (int j = 0; j < 2; ++j) {
            float4 v = make_float4(inter[0][j], inter[1][j], inter[2][j], inter[3][j]);
            *(float4*)&sT1[(c0 + j) * PITCH + m0] = v;
        }
        __syncthreads();

        // ---- G3: inter @ ii_w1, tanh (no bias)
        float t3[4][2];
        {
            float acc[4][2] = {{0.f, 0.f}, {0.f, 0.f}, {0.f, 0.f}, {0.f, 0.f}};
#pragma unroll 4
            for (int k = 0; k < 64; ++k) {
                float4 av = *(const float4*)&sT1[k * PITCH + m0];
                float2 wv = *(const float2*)&sWa[k * 64 + c0];
                acc[0][0] += av.x * wv.x; acc[0][1] += av.x * wv.y;
                acc[1][0] += av.y * wv.x; acc[1][1] += av.y * wv.y;
                acc[2][0] += av.z * wv.x; acc[2][1] += av.z * wv.y;
                acc[3][0] += av.w * wv.x; acc[3][1] += av.w * wv.y;
            }
#pragma unroll
            for (int mi = 0; mi < 4; ++mi)
#pragma unroll
                for (int j = 0; j < 2; ++j) t3[mi][j] = tanh_fast(acc[mi][j]);
        }
#pragma unroll
        for (int j = 0; j < 2; ++j) {
            float4 v = make_float4(t3[0][j], t3[1][j], t3[2][j], t3[3][j]);
            *(float4*)&sT0[(c0 + j) * PITCH + m0] = v;
        }
        __syncthreads();

        // ---- G4: @ ii_w2, tanh, atomic scatter by ind_i
        {
            float acc[4][2] = {{0.f, 0.f}, {0.f, 0.f}, {0.f, 0.f}, {0.f, 0.f}};
#pragma unroll 4
            for (int k = 0; k < 64; ++k) {
                float4 av = *(const float4*)&sT0[k * PITCH + m0];
                float2 wv = *(const float2*)&sWb[k * 64 + c0];
                acc[0][0] += av.x * wv.x; acc[0][1] += av.x * wv.y;
                acc[1][0] += av.y * wv.x; acc[1][1] += av.y * wv.y;
                acc[2][0] += av.z * wv.x; acc[2][1] += av.z * wv.y;
                acc[3][0] += av.w * wv.x; acc[3][1] += av.w * wv.y;
            }
#pragma unroll
            for (int mi = 0; mi < 4; ++mi) {
                int p = base + m0 + mi;
                if (p < N_PAIRS) {
                    int row = sIdx[m0 + mi];
                    atomicAdd(&accp[row * 64 + c0], tanh_fast(acc[mi][0]));
                    atomicAdd(&accp[row * 64 + c0 + 1], tanh_fast(acc[mi][1]));
                }
            }
        }
        __syncthreads();
    }
}

extern "C" void kernel_launch(void* const* d_in, const int* in_sizes, int n_in,
                              void* d_out, int out_size, void* d_ws, size_t ws_size,
                              hipStream_t stream) {
    const int* ind2 = (const int*)d_in[0];
    const float* prop = (const float*)d_in[1];
    const float* basis = (const float*)d_in[2];
    const float* pp0_w1 = (const float*)d_in[3];
    const float* pp0_b1 = (const float*)d_in[4];
    const float* pp_w1 = (const float*)d_in[5];
    const float* pp_b1 = (const float*)d_in[6];
    const float* pp_w2 = (const float*)d_in[7];
    const float* pp_b2 = (const float*)d_in[8];
    const float* pi_w1 = (const float*)d_in[9];
    const float* pi_b1 = (const float*)d_in[10];
    const float* pi_w2 = (const float*)d_in[11];
    const float* pi_b2 = (const float*)d_in[12];
    const float* ii_w1 = (const float*)d_in[13];
    const float* ii_w2 = (const float*)d_in[14];
    const float* res0_w = (const float*)d_in[15];
    const float* out_w1 = (const float*)d_in[16];
    const float* out_b1 = (const float*)d_in[17];
    const float* out_w2 = (const float*)d_in[18];
    const float* out_b2 = (const float*)d_in[19];
    const float* out_wo = (const float*)d_in[20];
    float* out = (float*)d_out;

    float* B0 = (float*)d_ws;
    float* B1 = B0 + N_ATOMS * 64;
    float* H = B1 + N_ATOMS * 64;
    float* pbuf[2] = {B0, B1};

    for (int d = 0; d < DEPTH; ++d) {
        float* acc = pbuf[d & 1];
        if (d == 0) {
            atom_mlp<16, true><<<N_ATOMS / 4, 256, 0, stream>>>(
                prop, pp0_w1, pp0_b1, pp_w2, pp_b2, res0_w, H, acc);
        } else {
            const float* pin = pbuf[(d - 1) & 1];
            atom_mlp<64, false><<<N_ATOMS / 4, 256, 0, stream>>>(
                pin, pp_w1 + (d - 1) * 4096, pp_b1 + (d - 1) * 64,
                pp_w2 + d * 4096, pp_b2 + d * 64, nullptr, H, acc);
        }
        pair_kernel<<<2048, 512, 0, stream>>>(
            H, ind2, basis,
            pi_w1 + d * 8192, pi_b1 + d * 64,
            pi_w2 + d * 16384, pi_b2 + d * 256,
            ii_w1 + d * 4096, ii_w2 + d * 4096, acc);
        out_kernel<<<N_ATOMS / 4, 256, 0, stream>>>(
            acc, out_w1 + d * 4096, out_b1 + d * 64,
            out_w2 + d * 4096, out_b2 + d * 64, out_wo + d * 64,
            out, d == 0 ? 1 : 0);
    }
}

// Round 5
// 1050.639 us; speedup vs baseline: 3.4009x; 3.4009x over previous
//
#include <hip/hip_runtime.h>
#include <hip/hip_bf16.h>

#define N_ATOMS 25000
#define N_PAIRS 500000
#define DEPTH 4

typedef _Float16 f16x8 __attribute__((ext_vector_type(8)));
typedef float f32x16 __attribute__((ext_vector_type(16)));
typedef unsigned short u16;

__device__ __forceinline__ float tanh_fast(float x) {
    // tanh(x) = 1 - 2/(exp(2x)+1); saturates correctly at +/-inf
    float e = __expf(2.0f * x);
    return 1.0f - 2.0f * __builtin_amdgcn_rcpf(e + 1.0f);
}

__device__ __forceinline__ void split_h(float x, u16& hi, u16& lo) {
    _Float16 h = (_Float16)x;                 // RNE
    _Float16 l = (_Float16)(x - (float)h);    // residual, RNE
    hi = *(u16*)&h;
    lo = *(u16*)&l;
}

// ---------------- prep: split weights to hi/lo fp16, fragment-major images
// img1 per depth: [hl][ntw][ks(8)][l(64)][j(8)]        = 16384 u16
// img2 per depth: [hl][ntw][t(4)][ks(4)][l][j]         = 32768 u16  (cols permuted: n=4*ch+t)
// imgab per depth: [stage][hl][ntw][ks(4)][l][j]       = 16384 u16
__global__ __launch_bounds__(256)
void prep_kernel(const float* __restrict__ piW1, const float* __restrict__ piW2,
                 const float* __restrict__ iiW1, const float* __restrict__ iiW2,
                 u16* __restrict__ img1, u16* __restrict__ img2, u16* __restrict__ imgab) {
    int gid = blockIdx.x * 256 + threadIdx.x;     // 512 blocks * 256 = 131072 = 4*32768
    int d = gid >> 15, e = gid & 32767;
    u16 hi, lo;
    if (e < 8192) {                 // W1 [k=128][n=64]
        int k = e >> 6, n = e & 63;
        split_h(piW1[d * 8192 + e], hi, lo);
        int ntw = n >> 5, colb = n & 31;
        int ks = k >> 4, lh = (k >> 3) & 1, j = k & 7;
        int off = ((ntw * 8 + ks) * 64 + lh * 32 + colb) * 8 + j;
        img1[d * 16384 + 0 * 8192 + off] = hi;
        img1[d * 16384 + 1 * 8192 + off] = lo;
    } else if (e < 24576) {         // W2 [k=64][n=256], permuted n = 4*ch + t
        int s = e - 8192;
        int k = s >> 8, n = s & 255;
        split_h(piW2[d * 16384 + s], hi, lo);
        int ch = n >> 2, t = n & 3;
        int ntw = ch >> 5, colb = ch & 31;
        int ks = k >> 4, lh = (k >> 3) & 1, j = k & 7;
        int off = (((ntw * 4 + t) * 4 + ks) * 64 + lh * 32 + colb) * 8 + j;
        img2[d * 32768 + 0 * 16384 + off] = hi;
        img2[d * 32768 + 1 * 16384 + off] = lo;
    } else {                        // Wa (stage0) / Wb (stage1), [k=64][n=64]
        int stage = (e < 28672) ? 0 : 1;
        int s = e - (stage ? 28672 : 24576);
        int k = s >> 6, n = s & 63;
        float x = stage ? iiW2[d * 4096 + s] : iiW1[d * 4096 + s];
        split_h(x, hi, lo);
        int ntw = n >> 5, colb = n & 31;
        int ks = k >> 4, lh = (k >> 3) & 1, j = k & 7;
        int off = ((ntw * 4 + ks) * 64 + lh * 32 + colb) * 8 + j;
        imgab[d * 16384 + (stage * 2 + 0) * 4096 + off] = hi;
        imgab[d * 16384 + (stage * 2 + 1) * 4096 + off] = lo;
    }
}

__global__ __launch_bounds__(256)
void prep_b2(const float* __restrict__ piB2, float* __restrict__ b2p) {
    int d = blockIdx.x, n = threadIdx.x;
    int ch = n >> 2, t = n & 3;
    int np = (ch >> 5) * 128 + t * 32 + (ch & 31);
    b2p[d * 256 + np] = piB2[d * 256 + n];
}

// ---------------- atom-level MLP (fp32 VALU), h stored split fp16 (hi=RNE, lo=RNE(h-hi))
template <int K, bool IS_D0>
__global__ __launch_bounds__(256)
void atom_mlp(const float* __restrict__ p_in,
              const float* __restrict__ W1, const float* __restrict__ b1,
              const float* __restrict__ W2, const float* __restrict__ b2,
              const float* __restrict__ res0_w,
              _Float16* __restrict__ h_hi, _Float16* __restrict__ h_lo,
              float* __restrict__ acc_out) {
    __shared__ float sP[4][64];
    __shared__ float sH[4][64];
    int tid = threadIdx.x;
    int al = tid >> 6, c = tid & 63;
    int a = blockIdx.x * 4 + al;
    if (c < K) sP[al][c] = p_in[a * K + c];
    __syncthreads();
    float s = b1[c];
#pragma unroll
    for (int k = 0; k < K; ++k) s += sP[al][k] * W1[k * 64 + c];
    float t1 = tanh_fast(s);
    float r;
    if (IS_D0) {
        r = 0.f;
#pragma unroll
        for (int k = 0; k < 16; ++k) r += sP[al][k] * res0_w[k * 64 + c];
    } else {
        r = sP[al][c];
    }
    acc_out[a * 64 + c] = r;
    sH[al][c] = t1;
    __syncthreads();
    float s2 = b2[c];
#pragma unroll
    for (int k = 0; k < 64; ++k) s2 += sH[al][k] * W2[k * 64 + c];
    float hv = tanh_fast(s2);
    _Float16 hb = (_Float16)hv;          // RNE hi
    h_hi[a * 64 + c] = hb;
    h_lo[a * 64 + c] = (_Float16)(hv - (float)hb);
}

// ---------------- output head (fp32)
__global__ __launch_bounds__(256)
void out_kernel(const float* __restrict__ p,
                const float* __restrict__ W1, const float* __restrict__ b1,
                const float* __restrict__ W2, const float* __restrict__ b2,
                const float* __restrict__ wo,
                float* __restrict__ out, int store) {
    __shared__ float sP[4][64];
    __shared__ float sH[4][64];
    int tid = threadIdx.x;
    int al = tid >> 6, c = tid & 63;
    int a = blockIdx.x * 4 + al;
    sP[al][c] = p[a * 64 + c];
    __syncthreads();
    float s = b1[c];
#pragma unroll
    for (int k = 0; k < 64; ++k) s += sP[al][k] * W1[k * 64 + c];
    sH[al][c] = tanh_fast(s);
    __syncthreads();
    float s2 = b2[c];
#pragma unroll
    for (int k = 0; k < 64; ++k) s2 += sH[al][k] * W2[k * 64 + c];
    float v = tanh_fast(s2) * wo[c];
#pragma unroll
    for (int off = 32; off > 0; off >>= 1) v += __shfl_down(v, off, 64);
    if (c == 0) {
        if (store) out[a] = v;
        else out[a] += v;
    }
}

// ---------------- fused pair pipeline: fp16 MFMA 32x32x16, split weights + split h_i
#define MFMA __builtin_amdgcn_mfma_f32_32x32x16_f16

__global__ __launch_bounds__(512, 2)
void pair_kernel(const _Float16* __restrict__ hhi,
                 const _Float16* __restrict__ hlo,
                 const int* __restrict__ ind2,
                 const float* __restrict__ basis,
                 const u16* __restrict__ img1,   // this depth
                 const u16* __restrict__ img2,
                 const u16* __restrict__ imgab,
                 const float* __restrict__ piB1,
                 const float* __restrict__ b2p,
                 float* __restrict__ accp) {
    __shared__ __attribute__((aligned(16))) _Float16 sW2[32768];   // 64 KB
    __shared__ __attribute__((aligned(16))) _Float16 sW1lo[8192];  // 16 KB
    __shared__ __attribute__((aligned(16))) _Float16 sA[16384];    // 32 KB  pij-hi frags / inter frags
    __shared__ __attribute__((aligned(16))) _Float16 sAlo[8192];   // 16 KB  pij-lo (i-half) frags
    __shared__ __attribute__((aligned(16))) _Float16 sPing[8192];  // 16 KB
    __shared__ float sBas[128 * 4];                                //  2 KB
    __shared__ int sIdx[128];                                      // 0.5 KB
    // total 146.5 KB -> 1 block/CU, 2 waves/SIMD

    const int tid = threadIdx.x;
    for (int i = tid; i < 4096; i += 512) ((uint4*)sW2)[i] = ((const uint4*)img2)[i];
    for (int i = tid; i < 1024; i += 512) ((uint4*)sW1lo)[i] = ((const uint4*)(img1 + 8192))[i];

    const int l = tid & 63;
    const int w = tid >> 6;
    const int mt = w >> 1, ntw = w & 1;
    const int col = l & 31, kg = l >> 5;
    const int ch = ntw * 32 + col;
    const int chks = ch >> 4, chlh = (ch >> 3) & 1, chj = ch & 7;   // fragment write coords

    // persistent register weights: W1-hi (8 frags), ii_w1/ii_w2 hi+lo (16 frags)
    f16x8 w1h[8], fa[2][4], fb[2][4];
#pragma unroll
    for (int ks = 0; ks < 8; ++ks)
        w1h[ks] = *(const f16x8*)(img1 + ntw * 4096 + ks * 512 + l * 8);
#pragma unroll
    for (int hl = 0; hl < 2; ++hl)
#pragma unroll
        for (int ks = 0; ks < 4; ++ks) {
            fa[hl][ks] = *(const f16x8*)(imgab + (0 * 2 + hl) * 4096 + ntw * 2048 + ks * 512 + l * 8);
            fb[hl][ks] = *(const f16x8*)(imgab + (1 * 2 + hl) * 4096 + ntw * 2048 + ks * 512 + l * 8);
        }
    const float b1v = piB1[ch];
    float b2v[4];
#pragma unroll
    for (int t = 0; t < 4; ++t) b2v[t] = b2p[ntw * 128 + t * 32 + col];

    const int nTiles = (N_PAIRS + 127) >> 7;

    auto gather = [&](int tile) {
        int base = tile << 7;
#pragma unroll
        for (int it = 0; it < 6; ++it) {
            int id = it * 512 + tid;
            if (id < 2048) {            // hi: both halves, K=128
                int m = id >> 4, half = (id >> 3) & 1, seg = id & 7;
                int p = base + m;
                uint4 v = make_uint4(0u, 0u, 0u, 0u);
                if (p < N_PAIRS) {
                    int row = ind2[2 * p + half];
                    v = *(const uint4*)(hhi + row * 64 + seg * 8);
                }
                int mtd = m >> 5, lrow = m & 31;
                int ks = half * 4 + (seg >> 1), lh = seg & 1;
                *(uint4*)(sA + ((mtd * 8 + ks) * 64 + lh * 32 + lrow) * 8) = v;
            } else {                    // lo: i-half only, K=64
                int e = id - 2048;
                int m = e >> 3, seg = e & 7;
                int p = base + m;
                uint4 v = make_uint4(0u, 0u, 0u, 0u);
                if (p < N_PAIRS) {
                    int row = ind2[2 * p];
                    v = *(const uint4*)(hlo + row * 64 + seg * 8);
                }
                int mtd = m >> 5, lrow = m & 31;
                int ks = seg >> 1, lh = seg & 1;
                *(uint4*)(sAlo + ((mtd * 4 + ks) * 64 + lh * 32 + lrow) * 8) = v;
            }
        }
    };
    gather(blockIdx.x);
    __syncthreads();

    for (int tile = blockIdx.x; tile < nTiles; tile += gridDim.x) {
        const int base = tile << 7;

        // ---- G1 phase: stage basis/idx; [128x128]@[128x64]+b1, tanh -> sPing
        if (tid < 128) {
            int p = base + tid;
            float4 bv = (p < N_PAIRS) ? ((const float4*)basis)[p] : make_float4(0.f, 0.f, 0.f, 0.f);
            *(float4*)&sBas[tid * 4] = bv;
            sIdx[tid] = (p < N_PAIRS) ? ind2[2 * p] : 0;
        }
        {
            f32x16 acc = {};
            const _Float16* ap = sA + mt * 4096 + l * 8;
            const _Float16* alop = sAlo + mt * 2048 + l * 8;
            const _Float16* blo = sW1lo + ntw * 4096 + l * 8;
#pragma unroll
            for (int ks = 0; ks < 8; ++ks) {
                f16x8 a = *(const f16x8*)(ap + ks * 512);
                acc = MFMA(a, w1h[ks], acc, 0, 0, 0);
                acc = MFMA(a, *(const f16x8*)(blo + ks * 512), acc, 0, 0, 0);
            }
#pragma unroll
            for (int ks = 0; ks < 4; ++ks) {   // h_i lo correction (i-half = k 0..63)
                f16x8 a = *(const f16x8*)(alop + ks * 512);
                acc = MFMA(a, w1h[ks], acc, 0, 0, 0);
            }
#pragma unroll
            for (int r = 0; r < 16; ++r) {
                int lrow = (r & 3) + 8 * (r >> 2) + 4 * kg;
                sPing[((mt * 4 + chks) * 64 + chlh * 32 + lrow) * 8 + chj] =
                    (_Float16)tanh_fast(acc[r] + b1v);
            }
        }
        __syncthreads();

        // ---- G2 phase: [128x64]@[64x256]+b2, tanh, in-lane basis contraction -> sA (inter frags)
        {
            f32x16 acc[4] = {{}, {}, {}, {}};
            const _Float16* ap = sPing + mt * 2048 + l * 8;
#pragma unroll
            for (int ks = 0; ks < 4; ++ks) {
                f16x8 a = *(const f16x8*)(ap + ks * 512);
#pragma unroll
                for (int t = 0; t < 4; ++t) {
                    acc[t] = MFMA(a, *(const f16x8*)(sW2 + ((ntw * 4 + t) * 4 + ks) * 512 + l * 8), acc[t], 0, 0, 0);
                    acc[t] = MFMA(a, *(const f16x8*)(sW2 + 16384 + ((ntw * 4 + t) * 4 + ks) * 512 + l * 8), acc[t], 0, 0, 0);
                }
            }
#pragma unroll
            for (int r = 0; r < 16; ++r) {
                int lrow = (r & 3) + 8 * (r >> 2) + 4 * kg;
                int row = mt * 32 + lrow;
                float4 bas = *(const float4*)&sBas[row * 4];
                float s = tanh_fast(acc[0][r] + b2v[0]) * bas.x
                        + tanh_fast(acc[1][r] + b2v[1]) * bas.y
                        + tanh_fast(acc[2][r] + b2v[2]) * bas.z
                        + tanh_fast(acc[3][r] + b2v[3]) * bas.w;
                sA[((mt * 4 + chks) * 64 + chlh * 32 + lrow) * 8 + chj] = (_Float16)s;
            }
        }
        __syncthreads();

        // ---- G3 phase: inter @ ii_w1, tanh -> sPing
        {
            f32x16 acc = {};
            const _Float16* ap = sA + mt * 2048 + l * 8;
#pragma unroll
            for (int ks = 0; ks < 4; ++ks) {
                f16x8 a = *(const f16x8*)(ap + ks * 512);
                acc = MFMA(a, fa[0][ks], acc, 0, 0, 0);
                acc = MFMA(a, fa[1][ks], acc, 0, 0, 0);
            }
#pragma unroll
            for (int r = 0; r < 16; ++r) {
                int lrow = (r & 3) + 8 * (r >> 2) + 4 * kg;
                sPing[((mt * 4 + chks) * 64 + chlh * 32 + lrow) * 8 + chj] =
                    (_Float16)tanh_fast(acc[r]);
            }
        }
        __syncthreads();

        // ---- G4 phase: @ ii_w2, tanh, atomic scatter; overlap next-tile gather
        {
            f16x8 afr[4];
            const _Float16* ap = sPing + mt * 2048 + l * 8;
#pragma unroll
            for (int ks = 0; ks < 4; ++ks) afr[ks] = *(const f16x8*)(ap + ks * 512);
            int idxr[16];
#pragma unroll
            for (int r = 0; r < 16; ++r)
                idxr[r] = sIdx[mt * 32 + (r & 3) + 8 * (r >> 2) + 4 * kg];

            gather(tile + gridDim.x);   // writes sA/sAlo only (dead until next G1)

            f32x16 acc = {};
#pragma unroll
            for (int ks = 0; ks < 4; ++ks) {
                acc = MFMA(afr[ks], fb[0][ks], acc, 0, 0, 0);
                acc = MFMA(afr[ks], fb[1][ks], acc, 0, 0, 0);
            }
#pragma unroll
            for (int r = 0; r < 16; ++r) {
                int lrow = (r & 3) + 8 * (r >> 2) + 4 * kg;
                int p = base + mt * 32 + lrow;
                if (p < N_PAIRS)
                    atomicAdd(&accp[idxr[r] * 64 + ch], tanh_fast(acc[r]));
            }
        }
        __syncthreads();
    }
}

extern "C" void kernel_launch(void* const* d_in, const int* in_sizes, int n_in,
                              void* d_out, int out_size, void* d_ws, size_t ws_size,
                              hipStream_t stream) {
    const int* ind2 = (const int*)d_in[0];
    const float* prop = (const float*)d_in[1];
    const float* basis = (const float*)d_in[2];
    const float* pp0_w1 = (const float*)d_in[3];
    const float* pp0_b1 = (const float*)d_in[4];
    const float* pp_w1 = (const float*)d_in[5];
    const float* pp_b1 = (const float*)d_in[6];
    const float* pp_w2 = (const float*)d_in[7];
    const float* pp_b2 = (const float*)d_in[8];
    const float* pi_w1 = (const float*)d_in[9];
    const float* pi_b1 = (const float*)d_in[10];
    const float* pi_w2 = (const float*)d_in[11];
    const float* pi_b2 = (const float*)d_in[12];
    const float* ii_w1 = (const float*)d_in[13];
    const float* ii_w2 = (const float*)d_in[14];
    const float* res0_w = (const float*)d_in[15];
    const float* out_w1 = (const float*)d_in[16];
    const float* out_b1 = (const float*)d_in[17];
    const float* out_w2 = (const float*)d_in[18];
    const float* out_b2 = (const float*)d_in[19];
    const float* out_wo = (const float*)d_in[20];
    float* out = (float*)d_out;

    // workspace layout
    float* B0 = (float*)d_ws;                            // 25000*64 f32
    float* B1 = B0 + N_ATOMS * 64;                       // 25000*64 f32
    _Float16* Hhi = (_Float16*)(B1 + N_ATOMS * 64);      // 25000*64 f16
    _Float16* Hlo = Hhi + N_ATOMS * 64;                  // 25000*64 f16
    u16* img1 = (u16*)(Hlo + N_ATOMS * 64);              // 4*16384 u16
    u16* img2 = img1 + 4 * 16384;                        // 4*32768 u16
    u16* imgab = img2 + 4 * 32768;                       // 4*16384 u16
    float* b2p = (float*)(imgab + 4 * 16384);            // 4*256 f32
    float* pbuf[2] = {B0, B1};

    prep_kernel<<<512, 256, 0, stream>>>(pi_w1, pi_w2, ii_w1, ii_w2, img1, img2, imgab);
    prep_b2<<<4, 256, 0, stream>>>(pi_b2, b2p);

    for (int d = 0; d < DEPTH; ++d) {
        float* acc = pbuf[d & 1];
        if (d == 0) {
            atom_mlp<16, true><<<N_ATOMS / 4, 256, 0, stream>>>(
                prop, pp0_w1, pp0_b1, pp_w2, pp_b2, res0_w, Hhi, Hlo, acc);
        } else {
            const float* pin = pbuf[(d - 1) & 1];
            atom_mlp<64, false><<<N_ATOMS / 4, 256, 0, stream>>>(
                pin, pp_w1 + (d - 1) * 4096, pp_b1 + (d - 1) * 64,
                pp_w2 + d * 4096, pp_b2 + d * 64, nullptr, Hhi, Hlo, acc);
        }
        pair_kernel<<<256, 512, 0, stream>>>(
            Hhi, Hlo, ind2, basis,
            img1 + d * 16384, img2 + d * 32768, imgab + d * 16384,
            pi_b1 + d * 64, b2p + d * 256, acc);
        out_kernel<<<N_ATOMS / 4, 256, 0, stream>>>(
            acc, out_w1 + d * 4096, out_b1 + d * 64,
            out_w2 + d * 4096, out_b2 + d * 64, out_wo + d * 64,
            out, d == 0 ? 1 : 0);
    }
}